// Round 2
// baseline (739.331 us; speedup 1.0000x reference)
//
#include <hip/hip_runtime.h>

#define S_LEN 2048
#define NHEAD 16
#define DHEAD 64
#define DMODEL 1024
#define NEGBIG 1000000000.0f

typedef float f32x4 __attribute__((ext_vector_type(4)));
typedef __bf16 bf16x8 __attribute__((ext_vector_type(8)));

// ---------------- W cast+transpose: W[K=1024][N=1024] f32 -> Wt[N][K] bf16 ----
__global__ __launch_bounds__(256) void transpose_cast_kernel(
    const float* __restrict__ W, __bf16* __restrict__ Wt)
{
    __shared__ float tile[32][33];
    int bx = blockIdx.x;              // n tile
    int by = blockIdx.y;              // k tile
    int tx = threadIdx.x;             // 0..31
    int ty = threadIdx.y;             // 0..7
    for (int i = 0; i < 32; i += 8)
        tile[ty + i][tx] = W[(size_t)(by * 32 + ty + i) * 1024 + bx * 32 + tx];
    __syncthreads();
    for (int i = 0; i < 32; i += 8)
        Wt[(size_t)(bx * 32 + ty + i) * 1024 + by * 32 + tx] = (__bf16)tile[tx][ty + i];
}

// ---------------- Projection GEMM ------------------------------------------
// C[m][n] = sum_k A[m][k] * Bt[n][k];  A fp32 [8192][1024], Bt bf16 [1024][1024]
// MODE 0: write C as bf16 [B][H][S][64]   (QW / KW)
// MODE 1: write C as bf16 [B][H][64][S]   (VW transposed)
template <int MODE>
__global__ __launch_bounds__(256) void proj_gemm_kernel(
    const float* __restrict__ A, const __bf16* __restrict__ Bt,
    __bf16* __restrict__ C)
{
    constexpr int K = 1024;
    __shared__ __align__(16) __bf16 As[128 * 32];
    __shared__ __align__(16) __bf16 Bs[128 * 32];

    int tid  = threadIdx.x;
    int bm   = blockIdx.x;
    int bn   = blockIdx.y;
    int wave = tid >> 6;
    int lane = tid & 63;
    int wm = (wave >> 1) * 64;
    int wn = (wave & 1) * 64;
    int lrow = lane & 15;
    int lk8  = (lane >> 4) * 8;

    f32x4 zero = {0.f, 0.f, 0.f, 0.f};
    f32x4 acc[4][4];
    for (int mt = 0; mt < 4; mt++)
        for (int nt = 0; nt < 4; nt++) acc[mt][nt] = zero;

    for (int k0 = 0; k0 < K; k0 += 32) {
        // stage A tile (128 x 32 fp32 -> bf16): 1024 float4 chunks
        for (int c = tid; c < 1024; c += 256) {
            int r = c >> 3, j = c & 7;
            float4 v = *(const float4*)&A[(size_t)(bm * 128 + r) * K + k0 + j * 4];
            __bf16* d = &As[r * 32 + j * 4];
            d[0] = (__bf16)v.x; d[1] = (__bf16)v.y;
            d[2] = (__bf16)v.z; d[3] = (__bf16)v.w;
        }
        // stage Bt tile (128 x 32 bf16): 512 16B chunks
        for (int c = tid; c < 512; c += 256) {
            int r = c >> 2, j = c & 3;
            *(float4*)&Bs[r * 32 + j * 8] =
                *(const float4*)&Bt[(size_t)(bn * 128 + r) * K + k0 + j * 8];
        }
        __syncthreads();

        bf16x8 af[4], bfv[4];
        for (int mt = 0; mt < 4; mt++)
            af[mt] = *(bf16x8*)&As[(wm + mt * 16 + lrow) * 32 + lk8];
        for (int nt = 0; nt < 4; nt++)
            bfv[nt] = *(bf16x8*)&Bs[(wn + nt * 16 + lrow) * 32 + lk8];
        for (int mt = 0; mt < 4; mt++)
            for (int nt = 0; nt < 4; nt++)
                acc[mt][nt] = __builtin_amdgcn_mfma_f32_16x16x32_bf16(
                    af[mt], bfv[nt], acc[mt][nt], 0, 0, 0);
        __syncthreads();
    }

    int rowoff = (lane >> 4) * 4;
    for (int mt = 0; mt < 4; mt++) {
        for (int nt = 0; nt < 4; nt++) {
            for (int reg = 0; reg < 4; reg++) {
                int rg = bm * 128 + wm + mt * 16 + rowoff + reg; // m = b*S + s
                int cg = bn * 128 + wn + nt * 16 + (lane & 15);  // n = h*64 + d
                int b = rg >> 11, s = rg & 2047;
                int h = cg >> 6,  d = cg & 63;
                __bf16 val = (__bf16)acc[mt][nt][reg];
                if (MODE == 0)
                    C[(((size_t)(b * NHEAD + h) * S_LEN) + s) * 64 + d] = val;
                else
                    C[(((size_t)(b * NHEAD + h) * 64) + d) * S_LEN + s] = val;
            }
        }
    }
}

// ---------------- Flash attention -------------------------------------------
// QW,KW: bf16 [B*H][S][64]; VT: bf16 [B*H][64][S]
// grid (32, 64): x = q block (reversed for load balance), y = b*H + h
//
// Reference semantics note: masks are additive -1e9 penalties in fp32, where
// (score - 1e9) rounds to EXACTLY -1e9. A query row whose whole causal window
// is kv-masked therefore softmaxes UNIFORMLY over {in-window masked keys} U
// {future unmasked keys}. We reproduce this by continuing the kv loop past
// the diagonal when any row in the block is degenerate (max logit ~ -1e9).
__global__ __launch_bounds__(256) void attn_kernel(
    const __bf16* __restrict__ QW, const __bf16* __restrict__ KW,
    const __bf16* __restrict__ VT, const float* __restrict__ v_mask,
    const float* __restrict__ q_mask, float* __restrict__ out)
{
    int qb = (S_LEN / 64 - 1) - blockIdx.x; // heavy blocks first
    int bh = blockIdx.y;
    int b = bh >> 4, h = bh & 15;

    __shared__ __align__(16) __bf16 Qs[64 * 64];
    __shared__ __align__(16) __bf16 Ks[64 * 64];
    __shared__ __align__(16) __bf16 Vts[64 * 64];
    __shared__ __align__(16) __bf16 Ps[64 * 64];
    __shared__ float vms[64];
    __shared__ int degflag;

    int tid  = threadIdx.x;
    int wave = tid >> 6;
    int lane = tid & 63;
    int row0 = wave * 16;
    int colbase = lane & 15;
    int rowoff  = (lane >> 4) * 4;
    int lk8     = (lane >> 4) * 8;

    // stage Q tile (contiguous 8KB)
    {
        const float4* src = (const float4*)(QW + ((size_t)bh * S_LEN + qb * 64) * 64);
        float4* dst = (float4*)Qs;
        dst[tid] = src[tid];
        dst[tid + 256] = src[tid + 256];
    }

    float m_i[4], l_i[4];
    f32x4 zero = {0.f, 0.f, 0.f, 0.f};
    f32x4 o_acc[4];
    for (int r = 0; r < 4; r++) { m_i[r] = -1e30f; l_i[r] = 0.f; }
    for (int nt = 0; nt < 4; nt++) o_acc[nt] = zero;

    auto kv_step = [&](int kb) {
        // stage K tile (contiguous 8KB)
        {
            const float4* src = (const float4*)(KW + ((size_t)bh * S_LEN + kb * 64) * 64);
            float4* dst = (float4*)Ks;
            dst[tid] = src[tid];
            dst[tid + 256] = src[tid + 256];
        }
        // stage V^T tile: rows dv (contig 128B each), col offset kb*64
        for (int c = tid; c < 512; c += 256) {
            int dv = c >> 3, j = c & 7;
            *(float4*)&Vts[dv * 64 + j * 8] =
                *(const float4*)&VT[((size_t)bh * 64 + dv) * S_LEN + kb * 64 + j * 8];
        }
        if (tid < 64) vms[tid] = v_mask[b * S_LEN + kb * 64 + tid];
        __syncthreads();

        // S = Q K^T  (strip: 16 rows x 64 cols per wave)
        f32x4 sacc[4];
        for (int nt = 0; nt < 4; nt++) sacc[nt] = zero;
        for (int kc = 0; kc < 2; kc++) {
            bf16x8 afr = *(bf16x8*)&Qs[(row0 + colbase) * 64 + kc * 32 + lk8];
            for (int nt = 0; nt < 4; nt++) {
                bf16x8 bfr = *(bf16x8*)&Ks[(nt * 16 + colbase) * 64 + kc * 32 + lk8];
                sacc[nt] = __builtin_amdgcn_mfma_f32_16x16x32_bf16(afr, bfr, sacc[nt], 0, 0, 0);
            }
        }

        // masks + online softmax (reference semantics: subtract 1e9 per mask)
        float lg[4][4];
        for (int nt = 0; nt < 4; nt++) {
            int col = nt * 16 + colbase;
            int kg = kb * 64 + col;
            float mpen = (1.0f - vms[col]) * NEGBIG;
            for (int reg = 0; reg < 4; reg++) {
                int qg = qb * 64 + row0 + rowoff + reg;
                float x = sacc[nt][reg] * 0.125f - mpen;
                if (kg > qg) x -= NEGBIG;
                lg[nt][reg] = x;
            }
        }
        for (int reg = 0; reg < 4; reg++) {
            float rmax = fmaxf(fmaxf(lg[0][reg], lg[1][reg]), fmaxf(lg[2][reg], lg[3][reg]));
            for (int off = 1; off <= 8; off <<= 1)
                rmax = fmaxf(rmax, __shfl_xor(rmax, off));
            float mnew  = fmaxf(m_i[reg], rmax);
            float alpha = __expf(m_i[reg] - mnew);
            float rsum = 0.f;
            for (int nt = 0; nt < 4; nt++) {
                float p = __expf(lg[nt][reg] - mnew);
                lg[nt][reg] = p;
                rsum += p;
            }
            for (int off = 1; off <= 8; off <<= 1)
                rsum += __shfl_xor(rsum, off);
            l_i[reg] = l_i[reg] * alpha + rsum;
            m_i[reg] = mnew;
            for (int nt = 0; nt < 4; nt++) o_acc[nt][reg] *= alpha;
        }
        // P -> LDS (each wave owns its 16 rows; no cross-wave dependency)
        for (int nt = 0; nt < 4; nt++)
            for (int reg = 0; reg < 4; reg++)
                Ps[(row0 + rowoff + reg) * 64 + nt * 16 + colbase] = (__bf16)lg[nt][reg];

        // O += P V   (B-fragment from transposed V tile)
        for (int kc = 0; kc < 2; kc++) {
            bf16x8 afr = *(bf16x8*)&Ps[(row0 + colbase) * 64 + kc * 32 + lk8];
            for (int nt = 0; nt < 4; nt++) {
                bf16x8 bfr = *(bf16x8*)&Vts[(nt * 16 + colbase) * 64 + kc * 32 + lk8];
                o_acc[nt] = __builtin_amdgcn_mfma_f32_16x16x32_bf16(afr, bfr, o_acc[nt], 0, 0, 0);
            }
        }
        __syncthreads(); // protect Ks/Vts/vms for next iteration
    };

    for (int kb = 0; kb <= qb; kb++) kv_step(kb);

    // Degenerate-row handling: if any row's running max is ~-1e9, its whole
    // causal window was masked; reference then includes future unmasked keys
    // (all logits exactly -1e9 in fp32). Continue over future blocks — for
    // normal rows exp(-1e9 - m) == 0, so they are unaffected.
    bool deg = false;
    for (int reg = 0; reg < 4; reg++) deg |= (m_i[reg] < -1e8f);
    if (tid == 0) degflag = 0;
    __syncthreads();
    if (deg) degflag = 1;
    __syncthreads();
    if (degflag) {
        for (int kb = qb + 1; kb < S_LEN / 64; kb++) kv_step(kb);
    }

    // epilogue: normalize, q_mask, write [B][S][H*64] fp32
    for (int reg = 0; reg < 4; reg++) {
        int qg = qb * 64 + row0 + rowoff + reg;
        float qm = q_mask[b * S_LEN + qg];
        float inv = qm / l_i[reg];
        for (int nt = 0; nt < 4; nt++)
            out[((size_t)(b * S_LEN + qg)) * (NHEAD * 64) + h * 64 + nt * 16 + colbase] =
                o_acc[nt][reg] * inv;
    }
}

// ---------------- launch -----------------------------------------------------
extern "C" void kernel_launch(void* const* d_in, const int* in_sizes, int n_in,
                              void* d_out, int out_size, void* d_ws, size_t ws_size,
                              hipStream_t stream)
{
    const float* q      = (const float*)d_in[0];
    const float* k      = (const float*)d_in[1];
    const float* v      = (const float*)d_in[2];
    const float* v_mask = (const float*)d_in[3];
    const float* q_mask = (const float*)d_in[4];
    const float* Wq     = (const float*)d_in[5];
    const float* Wk     = (const float*)d_in[6];
    const float* Wv     = (const float*)d_in[7];
    float* out = (float*)d_out;

    const size_t SZ_W = 1024 * 1024;          // 1M bf16
    const size_t SZ_P = (size_t)4 * NHEAD * S_LEN * 64; // 8.39M bf16
    __bf16* wqt = (__bf16*)d_ws;
    __bf16* wkt = wqt + SZ_W;
    __bf16* wvt = wkt + SZ_W;
    __bf16* qw  = wvt + SZ_W;
    __bf16* kw  = qw + SZ_P;
    __bf16* vwT = kw + SZ_P;

    dim3 tb(32, 8);
    transpose_cast_kernel<<<dim3(32, 32), tb, 0, stream>>>(Wq, wqt);
    transpose_cast_kernel<<<dim3(32, 32), tb, 0, stream>>>(Wk, wkt);
    transpose_cast_kernel<<<dim3(32, 32), tb, 0, stream>>>(Wv, wvt);

    proj_gemm_kernel<0><<<dim3(64, 8), 256, 0, stream>>>(q, wqt, qw);
    proj_gemm_kernel<0><<<dim3(64, 8), 256, 0, stream>>>(k, wkt, kw);
    proj_gemm_kernel<1><<<dim3(64, 8), 256, 0, stream>>>(v, wvt, vwT);

    attn_kernel<<<dim3(32, 64), 256, 0, stream>>>(qw, kw, vwT, v_mask, q_mask, out);
}

// Round 3
// 454.876 us; speedup vs baseline: 1.6253x; 1.6253x over previous
//
#include <hip/hip_runtime.h>

#define S_LEN 2048
#define NHEAD 16
#define NEGBIG 1000000000.0f

typedef float f32x4 __attribute__((ext_vector_type(4)));
typedef __bf16 bf16x8 __attribute__((ext_vector_type(8)));

#define AS1 __attribute__((address_space(1)))
#define AS3 __attribute__((address_space(3)))

// async 16B/lane global->LDS; lds base must be wave-uniform (dest = base + lane*16)
__device__ __forceinline__ void gl2lds16(const void* g, void* l) {
    __builtin_amdgcn_global_load_lds((const AS1 unsigned int*)g,
                                     (AS3 unsigned int*)l, 16, 0, 0);
}

// ---------------- cast+swizzle A: q,k,v fp32[8192][1024] -> bf16, 16B chunks
// within each 64-elem k-segment permuted by (chunk ^ row&7) ---------------
__global__ __launch_bounds__(256) void cast_swizzle_kernel(
    const float* __restrict__ q, const float* __restrict__ k,
    const float* __restrict__ v, __bf16* __restrict__ out)
{
    int gid = blockIdx.x * 256 + threadIdx.x;   // 3 * 8192 * 128 chunks
    int z   = gid >> 20;
    int rem = gid & 1048575;
    int r   = rem >> 7;
    int c   = rem & 127;                        // chunk of 8 elems within row
    const float* src = (z == 0 ? q : z == 1 ? k : v) + (size_t)r * 1024 + c * 8;
    float4 a = *(const float4*)src;
    float4 b = *(const float4*)(src + 4);
    bf16x8 t;
    t[0] = (__bf16)a.x; t[1] = (__bf16)a.y; t[2] = (__bf16)a.z; t[3] = (__bf16)a.w;
    t[4] = (__bf16)b.x; t[5] = (__bf16)b.y; t[6] = (__bf16)b.z; t[7] = (__bf16)b.w;
    int cp = (c & ~7) | ((c ^ r) & 7);          // swizzle within 64-elem segment
    *(bf16x8*)(out + (size_t)z * 8388608 + (size_t)r * 1024 + cp * 8) = t;
}

// ---------------- W transpose+cast+swizzle: W[k][n] f32 -> Wt[n][k] bf16 -----
__global__ __launch_bounds__(256) void transpose_cast_kernel(
    const float* __restrict__ W0, const float* __restrict__ W1,
    const float* __restrict__ W2, __bf16* __restrict__ Wt)
{
    int z = blockIdx.z;
    const float* W = (z == 0 ? W0 : z == 1 ? W1 : W2);
    __bf16* out = Wt + (size_t)z * 1048576;
    __shared__ float tile[32][33];
    int bx = blockIdx.x, by = blockIdx.y;
    int tid = threadIdx.x;
    int tx = tid & 31, ty = tid >> 5;
    for (int i = 0; i < 32; i += 8)
        tile[ty + i][tx] = W[(size_t)(by * 32 + ty + i) * 1024 + bx * 32 + tx];
    __syncthreads();
    if (tid < 128) {
        int nl = tid >> 2, kc = tid & 3;
        int n = bx * 32 + nl;
        int kbase = by * 32 + kc * 8;
        bf16x8 t;
        for (int j = 0; j < 8; j++) t[j] = (__bf16)tile[kc * 8 + j][nl];
        int cp = ((kbase >> 3) ^ n) & 7;
        *(bf16x8*)(out + (size_t)n * 1024 + (kbase & ~63) + cp * 8) = t;
    }
}

// ---------------- fused projection GEMM (z = 0:Q, 1:K, 2:V) -----------------
// C[m][n] = sum_k A[m][k]*Bt[n][k]; A,Bt bf16 swizzled; BK=64, tile 128x128
// z<2: write [B][H][S][64] with d-chunk swizzle by s&7
// z=2: write [B][H][64][S] with s-chunk swizzle by dv&7
__global__ __launch_bounds__(256, 3) void proj_gemm_kernel(
    const __bf16* __restrict__ Abf, const __bf16* __restrict__ Wt,
    __bf16* __restrict__ qw, __bf16* __restrict__ kw, __bf16* __restrict__ vt)
{
    int z = blockIdx.z;
    const __bf16* A = Abf + (size_t)z * 8388608;
    const __bf16* B = Wt + (size_t)z * 1048576;
    __shared__ __align__(16) __bf16 As[128 * 64];
    __shared__ __align__(16) __bf16 Bs[128 * 64];

    int tid = threadIdx.x;
    int bm = blockIdx.x, bn = blockIdx.y;
    int wave = tid >> 6, lane = tid & 63;
    int wm = (wave >> 1) * 64, wn = (wave & 1) * 64;
    int lrow = lane & 15;
    int q4 = lane >> 4;
    int x7 = lrow & 7;               // frag-read swizzle mask
    int l8r = lane >> 3, l8c = lane & 7;

    f32x4 zero = {0.f, 0.f, 0.f, 0.f};
    f32x4 acc[4][4];
    for (int mt = 0; mt < 4; mt++)
        for (int nt = 0; nt < 4; nt++) acc[mt][nt] = zero;

    for (int k0 = 0; k0 < 1024; k0 += 64) {
        for (int i = 0; i < 4; i++) {
            int row = wave * 32 + i * 8 + l8r;
            gl2lds16((const char*)A + ((size_t)(bm * 128 + row)) * 2048 + k0 * 2 + l8c * 16,
                     (char*)As + wave * 4096 + i * 1024);
            gl2lds16((const char*)B + ((size_t)(bn * 128 + row)) * 2048 + k0 * 2 + l8c * 16,
                     (char*)Bs + wave * 4096 + i * 1024);
        }
        __syncthreads();   // drains vmcnt -> tiles resident
        for (int kc = 0; kc < 2; kc++) {
            int sw = ((kc * 4 + q4) ^ x7) << 4;
            bf16x8 af[4], bfv[4];
            for (int mt = 0; mt < 4; mt++)
                af[mt] = *(const bf16x8*)((const char*)As + (wm + mt * 16 + lrow) * 128 + sw);
            for (int nt = 0; nt < 4; nt++)
                bfv[nt] = *(const bf16x8*)((const char*)Bs + (wn + nt * 16 + lrow) * 128 + sw);
            for (int mt = 0; mt < 4; mt++)
                for (int nt = 0; nt < 4; nt++)
                    acc[mt][nt] = __builtin_amdgcn_mfma_f32_16x16x32_bf16(
                        af[mt], bfv[nt], acc[mt][nt], 0, 0, 0);
        }
        __syncthreads();
    }

    int rowoff = q4 * 4;
    for (int mt = 0; mt < 4; mt++) {
        for (int nt = 0; nt < 4; nt++) {
            for (int reg = 0; reg < 4; reg++) {
                int rg = bm * 128 + wm + mt * 16 + rowoff + reg; // m = b*S + s
                int cg = bn * 128 + wn + nt * 16 + lrow;         // n = h*64 + d
                int b = rg >> 11, s = rg & 2047;
                int h = cg >> 6, d = cg & 63;
                __bf16 val = (__bf16)acc[mt][nt][reg];
                if (z < 2) {
                    int dp = (d & 7) | ((((d >> 3) ^ s) & 7) << 3);
                    (z == 0 ? qw : kw)[((size_t)(b * NHEAD + h) * S_LEN + s) * 64 + dp] = val;
                } else {
                    int j = s & 63;
                    int jp = (j & 7) | ((((j >> 3) ^ d) & 7) << 3);
                    vt[((size_t)(b * NHEAD + h) * 64 + d) * S_LEN + (s & ~63) + jp] = val;
                }
            }
        }
    }
}

// ---------------- flash attention --------------------------------------------
// QW,KW bf16 [B*H][S][64] swizzled; VT bf16 [B*H][64][S] swizzled
// one barrier per kv step; K/V double-buffered via global_load_lds prefetch
__global__ __launch_bounds__(256, 3) void attn_kernel(
    const __bf16* __restrict__ QW, const __bf16* __restrict__ KW,
    const __bf16* __restrict__ VT, const float* __restrict__ v_mask,
    const float* __restrict__ q_mask, float* __restrict__ out)
{
    int qb = 31 - blockIdx.x;    // heavy blocks first
    int bh = blockIdx.y;
    int b = bh >> 4, h = bh & 15;

    __shared__ __align__(16) __bf16 Qs[64 * 64];
    __shared__ __align__(16) __bf16 Ks[2][64 * 64];
    __shared__ __align__(16) __bf16 Vs[2][64 * 64];
    __shared__ __align__(16) __bf16 Ps[64 * 64];
    __shared__ int degflag;

    int tid = threadIdx.x;
    int wave = tid >> 6, lane = tid & 63;
    int row0 = wave * 16;
    int colbase = lane & 15;
    int q4 = lane >> 4;
    int rowoff = q4 * 4;
    int x7 = colbase & 7;            // frag-read swizzle mask
    int l8r = lane >> 3, l8c = lane & 7;

    const char* Qbase = (const char*)(QW + ((size_t)bh * S_LEN + qb * 64) * 64);
    const char* Kbase = (const char*)(KW + (size_t)bh * S_LEN * 64);
    const char* Vbase = (const char*)(VT + (size_t)bh * 64 * S_LEN);

    // stage Q (contiguous 8KB, pre-swizzled in global)
    for (int i = 0; i < 2; i++)
        gl2lds16(Qbase + wave * 2048 + i * 1024 + lane * 16,
                 (char*)Qs + wave * 2048 + i * 1024);

    auto prefetch = [&](int kb) {
        int bu = kb & 1;
        for (int i = 0; i < 2; i++)
            gl2lds16(Kbase + kb * 8192 + wave * 2048 + i * 1024 + lane * 16,
                     (char*)Ks[bu] + wave * 2048 + i * 1024);
        for (int i = 0; i < 2; i++) {
            int row = wave * 16 + i * 8 + l8r;   // dv row of VT
            gl2lds16(Vbase + (size_t)row * 4096 + kb * 128 + l8c * 16,
                     (char*)Vs[bu] + wave * 2048 + i * 1024);
        }
    };
    prefetch(0);

    float m_i[4], l_i[4];
    f32x4 zero = {0.f, 0.f, 0.f, 0.f};
    f32x4 o_acc[4];
    for (int r = 0; r < 4; r++) { m_i[r] = -1e30f; l_i[r] = 0.f; }
    for (int nt = 0; nt < 4; nt++) o_acc[nt] = zero;

    auto kv_step = [&](int kb, int last) {
        __syncthreads();             // buffer kb ready; other buffer free
        if (kb < last) prefetch(kb + 1);
        const char* Kb = (const char*)Ks[kb & 1];
        const char* Vb = (const char*)Vs[kb & 1];

        float pen[4];
        for (int nt = 0; nt < 4; nt++)
            pen[nt] = (1.0f - v_mask[b * S_LEN + kb * 64 + nt * 16 + colbase]) * NEGBIG;

        f32x4 sacc[4];
        for (int nt = 0; nt < 4; nt++) sacc[nt] = zero;
        for (int kc = 0; kc < 2; kc++) {
            int sw = ((kc * 4 + q4) ^ x7) << 4;
            bf16x8 afr = *(const bf16x8*)(Qs ? ((const char*)Qs + (row0 + colbase) * 128 + sw) : nullptr);
            for (int nt = 0; nt < 4; nt++) {
                bf16x8 bfr = *(const bf16x8*)(Kb + (nt * 16 + colbase) * 128 + sw);
                sacc[nt] = __builtin_amdgcn_mfma_f32_16x16x32_bf16(afr, bfr, sacc[nt], 0, 0, 0);
            }
        }

        float lg[4][4];
        for (int nt = 0; nt < 4; nt++) {
            int kg = kb * 64 + nt * 16 + colbase;
            for (int reg = 0; reg < 4; reg++) {
                int qg = qb * 64 + row0 + rowoff + reg;
                float x = sacc[nt][reg] * 0.125f - pen[nt];
                if (kg > qg) x -= NEGBIG;
                lg[nt][reg] = x;
            }
        }
        for (int reg = 0; reg < 4; reg++) {
            float rmax = fmaxf(fmaxf(lg[0][reg], lg[1][reg]), fmaxf(lg[2][reg], lg[3][reg]));
            for (int off = 1; off <= 8; off <<= 1)
                rmax = fmaxf(rmax, __shfl_xor(rmax, off));
            float mnew = fmaxf(m_i[reg], rmax);
            float alpha = __expf(m_i[reg] - mnew);
            float rsum = 0.f;
            for (int nt = 0; nt < 4; nt++) {
                float p = __expf(lg[nt][reg] - mnew);
                lg[nt][reg] = p;
                rsum += p;
            }
            for (int off = 1; off <= 8; off <<= 1)
                rsum += __shfl_xor(rsum, off);
            l_i[reg] = l_i[reg] * alpha + rsum;
            m_i[reg] = mnew;
            for (int nt = 0; nt < 4; nt++) o_acc[nt][reg] *= alpha;
        }
        // P -> LDS (swizzled; wave-private rows, no barrier needed)
        for (int nt = 0; nt < 4; nt++) {
            for (int reg = 0; reg < 4; reg++) {
                int r = row0 + rowoff + reg;
                int pc = (nt * 2 + (colbase >> 3)) ^ (r & 7);
                *((__bf16*)((char*)Ps + r * 128 + pc * 16 + (colbase & 7) * 2)) =
                    (__bf16)lg[nt][reg];
            }
        }
        for (int kc = 0; kc < 2; kc++) {
            int sw = ((kc * 4 + q4) ^ x7) << 4;
            bf16x8 afr = *(const bf16x8*)((const char*)Ps + (row0 + colbase) * 128 + sw);
            for (int nt = 0; nt < 4; nt++) {
                bf16x8 bfr = *(const bf16x8*)(Vb + (nt * 16 + colbase) * 128 + sw);
                o_acc[nt] = __builtin_amdgcn_mfma_f32_16x16x32_bf16(afr, bfr, o_acc[nt], 0, 0, 0);
            }
        }
    };

    for (int kb = 0; kb <= qb; kb++) kv_step(kb, qb);

    // degenerate rows (whole causal window masked): reference includes future
    // unmasked keys (all logits exactly -1e9 in fp32). Extend the loop; normal
    // rows are unaffected (exp underflows to 0).
    bool deg = false;
    for (int reg = 0; reg < 4; reg++) deg |= (m_i[reg] < -1e8f);
    if (tid == 0) degflag = 0;
    __syncthreads();
    if (deg) degflag = 1;
    __syncthreads();
    if (degflag && qb + 1 < 32) {
        prefetch(qb + 1);
        for (int kb = qb + 1; kb < 32; kb++) kv_step(kb, 31);
    }

    // epilogue: normalize, q_mask, write [B][S][H*64] fp32 (logical indices)
    for (int reg = 0; reg < 4; reg++) {
        int qg = qb * 64 + row0 + rowoff + reg;
        float qm = q_mask[b * S_LEN + qg];
        float inv = qm / l_i[reg];
        for (int nt = 0; nt < 4; nt++)
            out[((size_t)(b * S_LEN + qg)) * (NHEAD * 64) + h * 64 + nt * 16 + colbase] =
                o_acc[nt][reg] * inv;
    }
}

// ---------------- launch ------------------------------------------------------
extern "C" void kernel_launch(void* const* d_in, const int* in_sizes, int n_in,
                              void* d_out, int out_size, void* d_ws, size_t ws_size,
                              hipStream_t stream)
{
    const float* q      = (const float*)d_in[0];
    const float* k      = (const float*)d_in[1];
    const float* v      = (const float*)d_in[2];
    const float* v_mask = (const float*)d_in[3];
    const float* q_mask = (const float*)d_in[4];
    const float* Wq     = (const float*)d_in[5];
    const float* Wk     = (const float*)d_in[6];
    const float* Wv     = (const float*)d_in[7];
    float* out = (float*)d_out;

    __bf16* Abf = (__bf16*)d_ws;                 // 3 x 8192 x 1024
    __bf16* Wt  = Abf + (size_t)3 * 8388608;     // 3 x 1024 x 1024
    __bf16* qw  = Wt + (size_t)3 * 1048576;      // [B*H][S][64]
    __bf16* kw  = qw + (size_t)8388608;
    __bf16* vt  = kw + (size_t)8388608;          // [B*H][64][S]

    cast_swizzle_kernel<<<12288, 256, 0, stream>>>(q, k, v, Abf);
    transpose_cast_kernel<<<dim3(32, 32, 3), 256, 0, stream>>>(Wq, Wk, Wv, Wt);
    proj_gemm_kernel<<<dim3(64, 8, 3), 256, 0, stream>>>(Abf, Wt, qw, kw, vt);
    attn_kernel<<<dim3(32, 64), 256, 0, stream>>>(qw, kw, vt, v_mask, q_mask, out);
}

// Round 4
// 342.749 us; speedup vs baseline: 2.1571x; 1.3271x over previous
//
#include <hip/hip_runtime.h>

#define S_LEN 2048
#define NHEAD 16

typedef float f32x4 __attribute__((ext_vector_type(4)));
typedef __bf16 bf16x8 __attribute__((ext_vector_type(8)));

#define AS1 __attribute__((address_space(1)))
#define AS3 __attribute__((address_space(3)))

// async 16B/lane global->LDS; lds base wave-uniform (dest = base + lane*16)
__device__ __forceinline__ void gl2lds16(const void* g, void* l) {
    __builtin_amdgcn_global_load_lds((const AS1 unsigned int*)g,
                                     (AS3 unsigned int*)l, 16, 0, 0);
}

// ---------------- cast+swizzle A: q,k,v fp32[8192][1024] -> bf16, 16B chunks
// within each 64-elem k-segment permuted by (chunk ^ row&7) -------------------
__global__ __launch_bounds__(256) void cast_swizzle_kernel(
    const float* __restrict__ q, const float* __restrict__ k,
    const float* __restrict__ v, __bf16* __restrict__ out)
{
    int gid = blockIdx.x * 256 + threadIdx.x;
    int z   = gid >> 20;
    int rem = gid & 1048575;
    int r   = rem >> 7;
    int c   = rem & 127;
    const float* src = (z == 0 ? q : z == 1 ? k : v) + (size_t)r * 1024 + c * 8;
    float4 a = *(const float4*)src;
    float4 b = *(const float4*)(src + 4);
    bf16x8 t;
    t[0] = (__bf16)a.x; t[1] = (__bf16)a.y; t[2] = (__bf16)a.z; t[3] = (__bf16)a.w;
    t[4] = (__bf16)b.x; t[5] = (__bf16)b.y; t[6] = (__bf16)b.z; t[7] = (__bf16)b.w;
    int cp = (c & ~7) | ((c ^ r) & 7);
    *(bf16x8*)(out + (size_t)z * 8388608 + (size_t)r * 1024 + cp * 8) = t;
}

// ---------------- W transpose+cast+swizzle: W[k][n] f32 -> Wt[n][k] bf16 -----
__global__ __launch_bounds__(256) void transpose_cast_kernel(
    const float* __restrict__ W0, const float* __restrict__ W1,
    const float* __restrict__ W2, __bf16* __restrict__ Wt)
{
    int z = blockIdx.z;
    const float* W = (z == 0 ? W0 : z == 1 ? W1 : W2);
    __bf16* out = Wt + (size_t)z * 1048576;
    __shared__ float tile[32][33];
    int bx = blockIdx.x, by = blockIdx.y;
    int tid = threadIdx.x;
    int tx = tid & 31, ty = tid >> 5;
    for (int i = 0; i < 32; i += 8)
        tile[ty + i][tx] = W[(size_t)(by * 32 + ty + i) * 1024 + bx * 32 + tx];
    __syncthreads();
    if (tid < 128) {
        int nl = tid >> 2, kc = tid & 3;
        int n = bx * 32 + nl;
        int kbase = by * 32 + kc * 8;
        bf16x8 t;
        for (int j = 0; j < 8; j++) t[j] = (__bf16)tile[kc * 8 + j][nl];
        int cp = ((kbase >> 3) ^ n) & 7;
        *(bf16x8*)(out + (size_t)n * 1024 + (kbase & ~63) + cp * 8) = t;
    }
}

// ---------------- fused projection GEMM (z = 0:Q, 1:K, 2:V) ------------------
__global__ __launch_bounds__(256, 3) void proj_gemm_kernel(
    const __bf16* __restrict__ Abf, const __bf16* __restrict__ Wt,
    __bf16* __restrict__ qw, __bf16* __restrict__ kw, __bf16* __restrict__ vt)
{
    int z = blockIdx.z;
    const __bf16* A = Abf + (size_t)z * 8388608;
    const __bf16* B = Wt + (size_t)z * 1048576;
    __shared__ __align__(16) __bf16 As[128 * 64];
    __shared__ __align__(16) __bf16 Bs[128 * 64];

    int tid = threadIdx.x;
    int bm = blockIdx.x, bn = blockIdx.y;
    int wave = tid >> 6, lane = tid & 63;
    int wm = (wave >> 1) * 64, wn = (wave & 1) * 64;
    int lrow = lane & 15;
    int q4 = lane >> 4;
    int x7 = lrow & 7;
    int l8r = lane >> 3, l8c = lane & 7;

    f32x4 zero = {0.f, 0.f, 0.f, 0.f};
    f32x4 acc[4][4];
    for (int mt = 0; mt < 4; mt++)
        for (int nt = 0; nt < 4; nt++) acc[mt][nt] = zero;

    for (int k0 = 0; k0 < 1024; k0 += 64) {
        for (int i = 0; i < 4; i++) {
            int row = wave * 32 + i * 8 + l8r;
            gl2lds16((const char*)A + ((size_t)(bm * 128 + row)) * 2048 + k0 * 2 + l8c * 16,
                     (char*)As + wave * 4096 + i * 1024);
            gl2lds16((const char*)B + ((size_t)(bn * 128 + row)) * 2048 + k0 * 2 + l8c * 16,
                     (char*)Bs + wave * 4096 + i * 1024);
        }
        __syncthreads();
        for (int kc = 0; kc < 2; kc++) {
            int sw = ((kc * 4 + q4) ^ x7) << 4;
            bf16x8 af[4], bfv[4];
            for (int mt = 0; mt < 4; mt++)
                af[mt] = *(const bf16x8*)((const char*)As + (wm + mt * 16 + lrow) * 128 + sw);
            for (int nt = 0; nt < 4; nt++)
                bfv[nt] = *(const bf16x8*)((const char*)Bs + (wn + nt * 16 + lrow) * 128 + sw);
            for (int mt = 0; mt < 4; mt++)
                for (int nt = 0; nt < 4; nt++)
                    acc[mt][nt] = __builtin_amdgcn_mfma_f32_16x16x32_bf16(
                        af[mt], bfv[nt], acc[mt][nt], 0, 0, 0);
        }
        __syncthreads();
    }

    int rowoff = q4 * 4;
    for (int mt = 0; mt < 4; mt++) {
        for (int nt = 0; nt < 4; nt++) {
            for (int reg = 0; reg < 4; reg++) {
                int rg = bm * 128 + wm + mt * 16 + rowoff + reg;
                int cg = bn * 128 + wn + nt * 16 + lrow;
                int b = rg >> 11, s = rg & 2047;
                int h = cg >> 6, d = cg & 63;
                __bf16 val = (__bf16)acc[mt][nt][reg];
                if (z < 2) {
                    int dp = (d & 7) | ((((d >> 3) ^ s) & 7) << 3);
                    (z == 0 ? qw : kw)[((size_t)(b * NHEAD + h) * S_LEN + s) * 64 + dp] = val;
                } else {
                    int j = s & 63;
                    int jp = (j & 7) | ((((j >> 3) ^ d) & 7) << 3);
                    vt[((size_t)(b * NHEAD + h) * 64 + d) * S_LEN + (s & ~63) + jp] = val;
                }
            }
        }
    }
}

// ---------------- flash attention (constant-max softmax) ---------------------
// QW,KW bf16 [B*H][S][64] swizzled; VT bf16 [B*H][64][S] swizzled
// p = exp(s*0.125 - pen - 12): no per-step max/rescale (logits << 75 always).
// Degenerate rows (whole window masked -> l==0) fixed by an indicator-P pass.
__global__ __launch_bounds__(256, 4) void attn_kernel(
    const __bf16* __restrict__ QW, const __bf16* __restrict__ KW,
    const __bf16* __restrict__ VT, const float* __restrict__ v_mask,
    const float* __restrict__ q_mask, float* __restrict__ out)
{
    int qb = 31 - blockIdx.x;    // heavy blocks first
    int bh = blockIdx.y;
    int b = bh >> 4, h = bh & 15;

    __shared__ __align__(16) __bf16 Ks[2][4096];
    __shared__ __align__(16) __bf16 Vs[2][4096];
    __shared__ __align__(16) __bf16 Ps[4096];   // also: Q staging, then flag

    int tid = threadIdx.x;
    int wave = tid >> 6, lane = tid & 63;
    int row0 = wave * 16;
    int colbase = lane & 15;
    int q4 = lane >> 4;
    int rowoff = q4 * 4;
    int x7 = colbase & 7;
    int l8r = lane >> 3, l8c = lane & 7;

    const char* Qbase = (const char*)(QW + ((size_t)bh * S_LEN + qb * 64) * 64);
    const char* Kbase = (const char*)(KW + (size_t)bh * S_LEN * 64);
    const char* Vbase = (const char*)(VT + (size_t)bh * 64 * S_LEN);

    auto prefetchV = [&](int kb) {
        int bu = kb & 1;
        for (int i = 0; i < 2; i++) {
            int row = wave * 16 + i * 8 + l8r;
            gl2lds16(Vbase + (size_t)row * 4096 + kb * 128 + l8c * 16,
                     (char*)Vs[bu] + wave * 2048 + i * 1024);
        }
    };
    auto prefetch = [&](int kb) {
        int bu = kb & 1;
        for (int i = 0; i < 2; i++)
            gl2lds16(Kbase + kb * 8192 + wave * 2048 + i * 1024 + lane * 16,
                     (char*)Ks[bu] + wave * 2048 + i * 1024);
        prefetchV(kb);
    };

    // stage Q through Ps region (wave-private rows), prefetch tile 0
    for (int i = 0; i < 2; i++)
        gl2lds16(Qbase + wave * 2048 + i * 1024 + lane * 16,
                 (char*)Ps + wave * 2048 + i * 1024);
    prefetch(0);

    float vmc[4];
    for (int nt = 0; nt < 4; nt++)
        vmc[nt] = v_mask[b * S_LEN + nt * 16 + colbase];

    __syncthreads();    // Q + tile0 resident
    bf16x8 qfr[2];
    for (int kc = 0; kc < 2; kc++)
        qfr[kc] = *(const bf16x8*)((const char*)Ps + (row0 + colbase) * 128 +
                                   (((kc * 4 + q4) ^ x7) << 4));

    float l_i[4] = {0.f, 0.f, 0.f, 0.f};
    f32x4 zero = {0.f, 0.f, 0.f, 0.f};
    f32x4 o_acc[4];
    for (int nt = 0; nt < 4; nt++) o_acc[nt] = zero;

    for (int kb = 0; kb <= qb; kb++) {
        __syncthreads();             // tile kb ready; other buffer free
        if (kb < qb) prefetch(kb + 1);
        float penE[4];
        for (int nt = 0; nt < 4; nt++)
            penE[nt] = fmaf(1.0f - vmc[nt], 1.0e9f, 12.0f);
        if (kb < qb)
            for (int nt = 0; nt < 4; nt++)
                vmc[nt] = v_mask[b * S_LEN + (kb + 1) * 64 + nt * 16 + colbase];

        const char* Kb = (const char*)Ks[kb & 1];
        const char* Vb = (const char*)Vs[kb & 1];

        f32x4 sacc[4];
        for (int nt = 0; nt < 4; nt++) sacc[nt] = zero;
        for (int kc = 0; kc < 2; kc++) {
            int sw = ((kc * 4 + q4) ^ x7) << 4;
            for (int nt = 0; nt < 4; nt++) {
                bf16x8 bfr = *(const bf16x8*)(Kb + (nt * 16 + colbase) * 128 + sw);
                sacc[nt] = __builtin_amdgcn_mfma_f32_16x16x32_bf16(qfr[kc], bfr, sacc[nt], 0, 0, 0);
            }
        }

        float p[4][4];
        for (int nt = 0; nt < 4; nt++)
            for (int reg = 0; reg < 4; reg++)
                p[nt][reg] = __expf(fmaf(sacc[nt][reg], 0.125f, -penE[nt]));
        if (kb == qb) {   // causal zeroing only needed on the diagonal tile
            for (int nt = 0; nt < 4; nt++)
                for (int reg = 0; reg < 4; reg++)
                    if (nt * 16 + colbase > row0 + rowoff + reg) p[nt][reg] = 0.f;
        }
        for (int reg = 0; reg < 4; reg++)
            l_i[reg] += (p[0][reg] + p[1][reg]) + (p[2][reg] + p[3][reg]);

        // P -> LDS (swizzled, wave-private rows; no barrier needed)
        for (int nt = 0; nt < 4; nt++) {
            for (int reg = 0; reg < 4; reg++) {
                int r = row0 + rowoff + reg;
                int pc = (nt * 2 + (colbase >> 3)) ^ (r & 7);
                *((__bf16*)((char*)Ps + r * 128 + pc * 16 + (colbase & 7) * 2)) =
                    (__bf16)p[nt][reg];
            }
        }
        for (int kc = 0; kc < 2; kc++) {
            int sw = ((kc * 4 + q4) ^ x7) << 4;
            bf16x8 afr = *(const bf16x8*)((const char*)Ps + (row0 + colbase) * 128 + sw);
            for (int nt = 0; nt < 4; nt++) {
                bf16x8 bfr = *(const bf16x8*)(Vb + (nt * 16 + colbase) * 128 + sw);
                o_acc[nt] = __builtin_amdgcn_mfma_f32_16x16x32_bf16(afr, bfr, o_acc[nt], 0, 0, 0);
            }
        }
    }

    // one cross-lane l reduction for the whole kernel
    for (int reg = 0; reg < 4; reg++)
        for (int off = 1; off <= 8; off <<= 1)
            l_i[reg] += __shfl_xor(l_i[reg], off);

    // degenerate rows: l == 0 <=> entire causal window masked (real logits
    // can never underflow). Reference then softmaxes uniformly over
    // {window} U {unmasked future} (all at exactly -1e9 in fp32).
    bool deg[4];
    unsigned degmask = 0;
    for (int reg = 0; reg < 4; reg++) {
        deg[reg] = (l_i[reg] == 0.0f);
        if (deg[reg]) degmask |= 1u << (rowoff + reg);
    }
    degmask |= __shfl_xor(degmask, 16);
    degmask |= __shfl_xor(degmask, 32);

    int* flagp = (int*)Ps;           // row 0 of Ps = wave 0's private region
    if (tid == 0) *flagp = 0;
    __syncthreads();
    if (lane == 0 && degmask) *flagp = 1;
    __syncthreads();
    int dflag = *flagp;

    if (dflag) {
        // indicator-P pass, A-fragment built in registers (no LDS round trip)
        float l2 = 0.f;
        bool degrow = (degmask >> colbase) & 1;
        int qrow = qb * 64 + row0 + colbase;
        prefetchV(0);
        for (int kb = 0; kb < 32; kb++) {
            __syncthreads();
            if (kb < 31) prefetchV(kb + 1);
            const char* Vb = (const char*)Vs[kb & 1];
            for (int kc = 0; kc < 2; kc++) {
                const float* vmp = &v_mask[b * S_LEN + kb * 64 + kc * 32 + q4 * 8];
                float4 va = *(const float4*)vmp;
                float4 vb4 = *(const float4*)(vmp + 4);
                float vmj[8] = {va.x, va.y, va.z, va.w, vb4.x, vb4.y, vb4.z, vb4.w};
                int kg0 = kb * 64 + kc * 32 + q4 * 8;
                bf16x8 af;
                float cnt = 0.f;
                for (int j = 0; j < 8; j++) {
                    float ind = degrow ? ((kg0 + j <= qrow) ? 1.0f : vmj[j]) : 0.0f;
                    af[j] = (__bf16)ind;
                    cnt += ind;
                }
                l2 += cnt;
                int sw = ((kc * 4 + q4) ^ x7) << 4;
                for (int nt = 0; nt < 4; nt++) {
                    bf16x8 bfr = *(const bf16x8*)(Vb + (nt * 16 + colbase) * 128 + sw);
                    o_acc[nt] = __builtin_amdgcn_mfma_f32_16x16x32_bf16(af, bfr, o_acc[nt], 0, 0, 0);
                }
            }
        }
        l2 += __shfl_xor(l2, 16);
        l2 += __shfl_xor(l2, 32);
        for (int reg = 0; reg < 4; reg++)
            if (deg[reg]) l_i[reg] = __shfl(l2, rowoff + reg);
    }

    // epilogue: normalize, q_mask, write [B][S][H*64] fp32
    for (int reg = 0; reg < 4; reg++) {
        int qg = qb * 64 + row0 + rowoff + reg;
        float qm = q_mask[b * S_LEN + qg];
        float inv = qm / l_i[reg];
        for (int nt = 0; nt < 4; nt++)
            out[((size_t)(b * S_LEN + qg)) * (NHEAD * 64) + h * 64 + nt * 16 + colbase] =
                o_acc[nt][reg] * inv;
    }
}

// ---------------- launch ------------------------------------------------------
extern "C" void kernel_launch(void* const* d_in, const int* in_sizes, int n_in,
                              void* d_out, int out_size, void* d_ws, size_t ws_size,
                              hipStream_t stream)
{
    const float* q      = (const float*)d_in[0];
    const float* k      = (const float*)d_in[1];
    const float* v      = (const float*)d_in[2];
    const float* v_mask = (const float*)d_in[3];
    const float* q_mask = (const float*)d_in[4];
    const float* Wq     = (const float*)d_in[5];
    const float* Wk     = (const float*)d_in[6];
    const float* Wv     = (const float*)d_in[7];
    float* out = (float*)d_out;

    __bf16* Abf = (__bf16*)d_ws;                 // 3 x 8192 x 1024
    __bf16* Wt  = Abf + (size_t)3 * 8388608;     // 3 x 1024 x 1024
    __bf16* qw  = Wt + (size_t)3 * 1048576;      // [B*H][S][64]
    __bf16* kw  = qw + (size_t)8388608;
    __bf16* vt  = kw + (size_t)8388608;          // [B*H][64][S]

    cast_swizzle_kernel<<<12288, 256, 0, stream>>>(q, k, v, Abf);
    transpose_cast_kernel<<<dim3(32, 32, 3), 256, 0, stream>>>(Wq, Wk, Wv, Wt);
    proj_gemm_kernel<<<dim3(64, 8, 3), 256, 0, stream>>>(Abf, Wt, qw, kw, vt);
    attn_kernel<<<dim3(32, 64), 256, 0, stream>>>(qw, kw, vt, v_mask, q_mask, out);
}

// Round 5
// 327.241 us; speedup vs baseline: 2.2593x; 1.0474x over previous
//
#include <hip/hip_runtime.h>

#define S_LEN 2048
#define NHEAD 16

typedef float f32x4 __attribute__((ext_vector_type(4)));
typedef __bf16 bf16x8 __attribute__((ext_vector_type(8)));
typedef __bf16 bf16x4 __attribute__((ext_vector_type(4)));

#define AS1 __attribute__((address_space(1)))
#define AS3 __attribute__((address_space(3)))

// async 16B/lane global->LDS; lds base wave-uniform (dest = base + lane*16)
__device__ __forceinline__ void gl2lds16(const void* g, void* l) {
    __builtin_amdgcn_global_load_lds((const AS1 unsigned int*)g,
                                     (AS3 unsigned int*)l, 16, 0, 0);
}

// ---------------- cast+swizzle A: q,k,v fp32[8192][1024] -> bf16, 16B chunks
// within each 64-elem k-segment permuted by (chunk ^ row&7) -------------------
__global__ __launch_bounds__(256) void cast_swizzle_kernel(
    const float* __restrict__ q, const float* __restrict__ k,
    const float* __restrict__ v, __bf16* __restrict__ out)
{
    int gid = blockIdx.x * 256 + threadIdx.x;
    int z   = gid >> 20;
    int rem = gid & 1048575;
    int r   = rem >> 7;
    int c   = rem & 127;
    const float* src = (z == 0 ? q : z == 1 ? k : v) + (size_t)r * 1024 + c * 8;
    float4 a = *(const float4*)src;
    float4 b = *(const float4*)(src + 4);
    bf16x8 t;
    t[0] = (__bf16)a.x; t[1] = (__bf16)a.y; t[2] = (__bf16)a.z; t[3] = (__bf16)a.w;
    t[4] = (__bf16)b.x; t[5] = (__bf16)b.y; t[6] = (__bf16)b.z; t[7] = (__bf16)b.w;
    int cp = (c & ~7) | ((c ^ r) & 7);
    *(bf16x8*)(out + (size_t)z * 8388608 + (size_t)r * 1024 + cp * 8) = t;
}

// ---------------- W transpose+cast+swizzle: W[k][n] f32 -> Wt[n][k] bf16 -----
__global__ __launch_bounds__(256) void transpose_cast_kernel(
    const float* __restrict__ W0, const float* __restrict__ W1,
    const float* __restrict__ W2, __bf16* __restrict__ Wt)
{
    int z = blockIdx.z;
    const float* W = (z == 0 ? W0 : z == 1 ? W1 : W2);
    __bf16* out = Wt + (size_t)z * 1048576;
    __shared__ float tile[32][33];
    int bx = blockIdx.x, by = blockIdx.y;
    int tid = threadIdx.x;
    int tx = tid & 31, ty = tid >> 5;
    for (int i = 0; i < 32; i += 8)
        tile[ty + i][tx] = W[(size_t)(by * 32 + ty + i) * 1024 + bx * 32 + tx];
    __syncthreads();
    if (tid < 128) {
        int nl = tid >> 2, kc = tid & 3;
        int n = bx * 32 + nl;
        int kbase = by * 32 + kc * 8;
        bf16x8 t;
        for (int j = 0; j < 8; j++) t[j] = (__bf16)tile[kc * 8 + j][nl];
        int cp = ((kbase >> 3) ^ n) & 7;
        *(bf16x8*)(out + (size_t)n * 1024 + (kbase & ~63) + cp * 8) = t;
    }
}

// ---------------- fused projection GEMM (z = 0:Q, 1:K, 2:V) ------------------
// LDS-staged coalesced epilogue: C-tile assembled in LDS, stored as dwordx4.
__global__ __launch_bounds__(256, 3) void proj_gemm_kernel(
    const __bf16* __restrict__ Abf, const __bf16* __restrict__ Wt,
    __bf16* __restrict__ qw, __bf16* __restrict__ kw, __bf16* __restrict__ vt)
{
    int z = blockIdx.z;
    const __bf16* A = Abf + (size_t)z * 8388608;
    const __bf16* B = Wt + (size_t)z * 1048576;
    __shared__ __align__(16) char smem[34816];   // stage: As|Bs; epilogue: T
    __bf16* As = (__bf16*)smem;
    __bf16* Bs = (__bf16*)(smem + 16384);

    int tid = threadIdx.x;
    int bm = blockIdx.x, bn = blockIdx.y;
    int wave = tid >> 6, lane = tid & 63;
    int wm = (wave >> 1) * 64, wn = (wave & 1) * 64;
    int lrow = lane & 15;
    int q4 = lane >> 4;
    int x7 = lrow & 7;
    int l8r = lane >> 3, l8c = lane & 7;

    f32x4 zero = {0.f, 0.f, 0.f, 0.f};
    f32x4 acc[4][4];
    for (int mt = 0; mt < 4; mt++)
        for (int nt = 0; nt < 4; nt++) acc[mt][nt] = zero;

    for (int k0 = 0; k0 < 1024; k0 += 64) {
        for (int i = 0; i < 4; i++) {
            int row = wave * 32 + i * 8 + l8r;
            gl2lds16((const char*)A + ((size_t)(bm * 128 + row)) * 2048 + k0 * 2 + l8c * 16,
                     (char*)As + wave * 4096 + i * 1024);
            gl2lds16((const char*)B + ((size_t)(bn * 128 + row)) * 2048 + k0 * 2 + l8c * 16,
                     (char*)Bs + wave * 4096 + i * 1024);
        }
        __syncthreads();
        for (int kc = 0; kc < 2; kc++) {
            int sw = ((kc * 4 + q4) ^ x7) << 4;
            bf16x8 af[4], bfv[4];
            for (int mt = 0; mt < 4; mt++)
                af[mt] = *(const bf16x8*)((const char*)As + (wm + mt * 16 + lrow) * 128 + sw);
            for (int nt = 0; nt < 4; nt++)
                bfv[nt] = *(const bf16x8*)((const char*)Bs + (wn + nt * 16 + lrow) * 128 + sw);
            for (int mt = 0; mt < 4; mt++)
                for (int nt = 0; nt < 4; nt++)
                    acc[mt][nt] = __builtin_amdgcn_mfma_f32_16x16x32_bf16(
                        af[mt], bfv[nt], acc[mt][nt], 0, 0, 0);
        }
        __syncthreads();
    }
    // after final barrier, all fragment reads done -> reuse smem as T
    __bf16* T = (__bf16*)smem;     // row stride 136 elems (272B, 16B-aligned)

    int rowoff = q4 * 4;
    int b = bm >> 4;
    int s_base = (bm & 15) * 128;
    if (z < 2) {
        // T[s_local][n_local(=h_local*64+dp)]
        for (int mt = 0; mt < 4; mt++) {
            for (int nt = 0; nt < 4; nt++) {
                int n_local = wn + nt * 16 + lrow;
                int hl = n_local >> 6, d = n_local & 63;
                for (int reg = 0; reg < 4; reg++) {
                    int s_local = wm + mt * 16 + rowoff + reg;
                    int s = s_base + s_local;
                    int dp = (d & 7) | ((((d >> 3) ^ s) & 7) << 3);
                    T[s_local * 136 + hl * 64 + dp] = (__bf16)acc[mt][nt][reg];
                }
            }
        }
        __syncthreads();
        // copy out: 2048 x 16B chunks, coalesced
        char* gq = (char*)(z == 0 ? qw : kw);
        for (int i = 0; i < 8; i++) {
            int id = tid + i * 256;
            int hl = id >> 10, r = (id >> 3) & 127, j = id & 7;
            float4 val = *(float4*)((char*)T + r * 272 + hl * 128 + j * 16);
            *(float4*)(gq + ((size_t)((b * 16 + bn * 2 + hl) * 2048) + s_base + r) * 128
                          + j * 16) = val;
        }
    } else {
        // T2[n_local][seg*64 + jp]  (s-swizzled within 64-elem segments)
        for (int mt = 0; mt < 4; mt++) {
            int s0 = wm + mt * 16 + rowoff;      // 4 consecutive s per reg
            int seg = s0 >> 6, j0 = s0 & 63;
            for (int nt = 0; nt < 4; nt++) {
                int n_local = wn + nt * 16 + lrow;
                int d = n_local & 63;
                int hi = ((j0 >> 3) ^ d) & 7;
                bf16x4 pk;
                for (int reg = 0; reg < 4; reg++) pk[reg] = (__bf16)acc[mt][nt][reg];
                *(bf16x4*)&T[n_local * 136 + seg * 64 + hi * 8 + (j0 & 7)] = pk;
            }
        }
        __syncthreads();
        char* gv = (char*)vt;
        for (int i = 0; i < 8; i++) {
            int id = tid + i * 256;
            int nl = id >> 4, j = id & 15;
            int hl = nl >> 6, dv = nl & 63;
            float4 val = *(float4*)((char*)T + nl * 272 + j * 16);
            *(float4*)(gv + (((size_t)((b * 16 + bn * 2 + hl) * 64 + dv)) * 2048 + s_base) * 2
                          + j * 16) = val;
        }
    }
}

// ---------------- flash attention (constant-max softmax, S^T layout) ---------
// QW,KW bf16 [B*H][S][64] swizzled; VT bf16 [B*H][64][S] swizzled
// S^T = MFMA(A=K, B=Q): lane owns query m=lane&15, keys q4*4+reg (consecutive)
// p = exp(s*0.125 - pen - 12): no per-step max/rescale (|logits| << 75).
// Degenerate rows (whole window masked -> l==0) fixed by indicator-P pass.
__global__ __launch_bounds__(256, 4) void attn_kernel(
    const __bf16* __restrict__ QW, const __bf16* __restrict__ KW,
    const __bf16* __restrict__ VT, const float* __restrict__ v_mask,
    const float* __restrict__ q_mask, float* __restrict__ out)
{
    int qb = 31 - blockIdx.x;    // heavy blocks first
    int bh = blockIdx.y;
    int b = bh >> 4, h = bh & 15;

    __shared__ __align__(16) __bf16 Ks[2][4096];
    __shared__ __align__(16) __bf16 Vs[2][4096];
    __shared__ __align__(16) __bf16 Ps[4096];   // Q staging, P tile, flag

    int tid = threadIdx.x;
    int wave = tid >> 6, lane = tid & 63;
    int row0 = wave * 16;
    int mloc = lane & 15;            // this lane's query row (local)
    int q4 = lane >> 4;
    int rowoff = q4 * 4;
    int x7 = mloc & 7;
    int l8r = lane >> 3, l8c = lane & 7;

    const char* Qbase = (const char*)(QW + ((size_t)bh * S_LEN + qb * 64) * 64);
    const char* Kbase = (const char*)(KW + (size_t)bh * S_LEN * 64);
    const char* Vbase = (const char*)(VT + (size_t)bh * 64 * S_LEN);

    auto prefetchV = [&](int kb) {
        int bu = kb & 1;
        for (int i = 0; i < 2; i++) {
            int row = wave * 16 + i * 8 + l8r;
            gl2lds16(Vbase + (size_t)row * 4096 + kb * 128 + l8c * 16,
                     (char*)Vs[bu] + wave * 2048 + i * 1024);
        }
    };
    auto prefetch = [&](int kb) {
        int bu = kb & 1;
        for (int i = 0; i < 2; i++)
            gl2lds16(Kbase + kb * 8192 + wave * 2048 + i * 1024 + lane * 16,
                     (char*)Ks[bu] + wave * 2048 + i * 1024);
        prefetchV(kb);
    };

    // stage Q through Ps region, prefetch tile 0
    for (int i = 0; i < 2; i++)
        gl2lds16(Qbase + wave * 2048 + i * 1024 + lane * 16,
                 (char*)Ps + wave * 2048 + i * 1024);
    prefetch(0);

    float4 vm4[4];
    for (int nt = 0; nt < 4; nt++)
        vm4[nt] = *(const float4*)&v_mask[b * S_LEN + nt * 16 + q4 * 4];

    __syncthreads();    // Q + tile0 resident
    bf16x8 qfr[2];
    for (int kc = 0; kc < 2; kc++)
        qfr[kc] = *(const bf16x8*)((const char*)Ps + (row0 + mloc) * 128 +
                                   (((kc * 4 + q4) ^ x7) << 4));

    float l_part = 0.f;
    f32x4 zero = {0.f, 0.f, 0.f, 0.f};
    f32x4 o_acc[4];
    for (int nt = 0; nt < 4; nt++) o_acc[nt] = zero;

    for (int kb = 0; kb <= qb; kb++) {
        __syncthreads();             // tile kb ready; other buffer free
        if (kb < qb) prefetch(kb + 1);
        float pen[4][4];
        for (int nt = 0; nt < 4; nt++) {
            pen[nt][0] = fmaf(1.0f - vm4[nt].x, 1.0e9f, 12.0f);
            pen[nt][1] = fmaf(1.0f - vm4[nt].y, 1.0e9f, 12.0f);
            pen[nt][2] = fmaf(1.0f - vm4[nt].z, 1.0e9f, 12.0f);
            pen[nt][3] = fmaf(1.0f - vm4[nt].w, 1.0e9f, 12.0f);
        }
        if (kb < qb)
            for (int nt = 0; nt < 4; nt++)
                vm4[nt] = *(const float4*)&v_mask[b * S_LEN + (kb + 1) * 64 + nt * 16 + q4 * 4];

        const char* Kb = (const char*)Ks[kb & 1];
        const char* Vb = (const char*)Vs[kb & 1];

        // S^T tiles: sacc[nt][reg] = score(key c = kb*64+nt*16+q4*4+reg,
        //                                  query m = row0+mloc)
        f32x4 sacc[4];
        for (int nt = 0; nt < 4; nt++) sacc[nt] = zero;
        for (int kc = 0; kc < 2; kc++) {
            int sw = ((kc * 4 + q4) ^ x7) << 4;
            for (int nt = 0; nt < 4; nt++) {
                bf16x8 kfr = *(const bf16x8*)(Kb + (nt * 16 + mloc) * 128 + sw);
                sacc[nt] = __builtin_amdgcn_mfma_f32_16x16x32_bf16(kfr, qfr[kc], sacc[nt], 0, 0, 0);
            }
        }

        float p[4][4];
        for (int nt = 0; nt < 4; nt++)
            for (int reg = 0; reg < 4; reg++)
                p[nt][reg] = __expf(fmaf(sacc[nt][reg], 0.125f, -pen[nt][reg]));
        if (kb == qb) {   // causal zeroing on the diagonal tile
            for (int nt = 0; nt < 4; nt++)
                for (int reg = 0; reg < 4; reg++)
                    if (nt * 16 + rowoff + reg > row0 + mloc) p[nt][reg] = 0.f;
        }
        for (int nt = 0; nt < 4; nt++)
            l_part += (p[nt][0] + p[nt][1]) + (p[nt][2] + p[nt][3]);

        // P -> LDS: 4 consecutive keys pack into one b64 write per nt
        for (int nt = 0; nt < 4; nt++) {
            bf16x4 pk;
            for (int reg = 0; reg < 4; reg++) pk[reg] = (__bf16)p[nt][reg];
            int s0 = nt * 32 + q4 * 8;           // byte offset of first key*2
            int pc = (s0 >> 4) ^ x7;
            *(bf16x4*)((char*)Ps + (row0 + mloc) * 128 + pc * 16 + (s0 & 8)) = pk;
        }
        for (int kc = 0; kc < 2; kc++) {
            int sw = ((kc * 4 + q4) ^ x7) << 4;
            bf16x8 afr = *(const bf16x8*)((const char*)Ps + (row0 + mloc) * 128 + sw);
            for (int nt = 0; nt < 4; nt++) {
                bf16x8 bfr = *(const bf16x8*)(Vb + (nt * 16 + mloc) * 128 + sw);
                o_acc[nt] = __builtin_amdgcn_mfma_f32_16x16x32_bf16(afr, bfr, o_acc[nt], 0, 0, 0);
            }
        }
    }

    // finalize l: lane holds partial for query m=mloc over its 64-key slices
    l_part += __shfl_xor(l_part, 16);
    l_part += __shfl_xor(l_part, 32);

    // degenerate rows: l==0 <=> entire causal window masked. Reference then
    // softmaxes uniformly over {window} U {unmasked future} (all at -1e9).
    unsigned long long bal = __ballot(l_part == 0.0f);
    unsigned degmask = (unsigned)(bal & 0xFFFFull);

    int* flagp = (int*)Ps;
    if (tid == 0) *flagp = 0;
    __syncthreads();
    if (lane == 0 && degmask) *flagp = 1;
    __syncthreads();
    int dflag = *flagp;

    if (dflag) {
        float l2 = 0.f;
        bool degrow = (degmask >> mloc) & 1;
        int qrow = qb * 64 + row0 + mloc;
        prefetchV(0);
        for (int kb = 0; kb < 32; kb++) {
            __syncthreads();
            if (kb < 31) prefetchV(kb + 1);
            const char* Vb = (const char*)Vs[kb & 1];
            for (int kc = 0; kc < 2; kc++) {
                const float* vmp = &v_mask[b * S_LEN + kb * 64 + kc * 32 + q4 * 8];
                float4 va = *(const float4*)vmp;
                float4 vb4 = *(const float4*)(vmp + 4);
                float vmj[8] = {va.x, va.y, va.z, va.w, vb4.x, vb4.y, vb4.z, vb4.w};
                int kg0 = kb * 64 + kc * 32 + q4 * 8;
                bf16x8 af;
                float cnt = 0.f;
                for (int j = 0; j < 8; j++) {
                    float ind = degrow ? ((kg0 + j <= qrow) ? 1.0f : vmj[j]) : 0.0f;
                    af[j] = (__bf16)ind;
                    cnt += ind;
                }
                l2 += cnt;
                int sw = ((kc * 4 + q4) ^ x7) << 4;
                for (int nt = 0; nt < 4; nt++) {
                    bf16x8 bfr = *(const bf16x8*)(Vb + (nt * 16 + mloc) * 128 + sw);
                    o_acc[nt] = __builtin_amdgcn_mfma_f32_16x16x32_bf16(af, bfr, o_acc[nt], 0, 0, 0);
                }
            }
        }
        l2 += __shfl_xor(l2, 16);
        l2 += __shfl_xor(l2, 32);
        if (l_part == 0.0f) l_part = l2;
    }

    // epilogue: o_acc rows m = rowoff+reg; l lives in lane (m) -> bpermute
    for (int reg = 0; reg < 4; reg++) {
        float lv = __shfl(l_part, rowoff + reg);
        int qg = qb * 64 + row0 + rowoff + reg;
        float qm = q_mask[b * S_LEN + qg];
        float inv = qm / lv;
        for (int nt = 0; nt < 4; nt++)
            out[((size_t)(b * S_LEN + qg)) * (NHEAD * 64) + h * 64 + nt * 16 + mloc] =
                o_acc[nt][reg] * inv;
    }
}

// ---------------- launch ------------------------------------------------------
extern "C" void kernel_launch(void* const* d_in, const int* in_sizes, int n_in,
                              void* d_out, int out_size, void* d_ws, size_t ws_size,
                              hipStream_t stream)
{
    const float* q      = (const float*)d_in[0];
    const float* k      = (const float*)d_in[1];
    const float* v      = (const float*)d_in[2];
    const float* v_mask = (const float*)d_in[3];
    const float* q_mask = (const float*)d_in[4];
    const float* Wq     = (const float*)d_in[5];
    const float* Wk     = (const float*)d_in[6];
    const float* Wv     = (const float*)d_in[7];
    float* out = (float*)d_out;

    __bf16* Abf = (__bf16*)d_ws;                 // 3 x 8192 x 1024
    __bf16* Wt  = Abf + (size_t)3 * 8388608;     // 3 x 1024 x 1024
    __bf16* qw  = Wt + (size_t)3 * 1048576;      // [B*H][S][64]
    __bf16* kw  = qw + (size_t)8388608;
    __bf16* vt  = kw + (size_t)8388608;          // [B*H][64][S]

    cast_swizzle_kernel<<<12288, 256, 0, stream>>>(q, k, v, Abf);
    transpose_cast_kernel<<<dim3(32, 32, 3), 256, 0, stream>>>(Wq, Wk, Wv, Wt);
    proj_gemm_kernel<<<dim3(64, 8, 3), 256, 0, stream>>>(Abf, Wt, qw, kw, vt);
    attn_kernel<<<dim3(32, 64), 256, 0, stream>>>(qw, kw, vt, v_mask, q_mask, out);
}